// Round 17
// baseline (4387.882 us; speedup 1.0000x reference)
//
#include <hip/hip_runtime.h>

#define NTOK 32768
#define NE   2048
#define EDIM 128
#define NQ   4

#define TOKT 64                  // tokens per block
#define CHCODES 64               // codes per staged chunk (16 KB bf16)
#define NCHUNK (NE / CHCODES)    // 32
#define NWARM 8                  // phase-A chunks (warmup, redone in phase C)
#define CAP 24
#define MARGIN 0.25f             // d-space margin (r11-proven)

typedef __attribute__((ext_vector_type(8))) short short8v;   // 8 bf16
typedef __attribute__((ext_vector_type(4))) float f32x4;

__device__ __forceinline__ unsigned short bf16rne(float x) {
    unsigned u = __float_as_uint(x);
    unsigned r = 0x7FFFu + ((u >> 16) & 1u);
    return (unsigned short)((u + r) >> 16);
}

__device__ __forceinline__ void gld16(const void* g, const void* l) {
    __builtin_amdgcn_global_load_lds(
        (const __attribute__((address_space(1))) unsigned int*)g,
        (__attribute__((address_space(3))) unsigned int*)l, 16, 0, 0);
}

#define MFMA_BF16 __builtin_amdgcn_mfma_f32_16x16x32_bf16

// ---------------------------------------------------------------------------
// prep: per-code fp32 norms (identical serial chain to rounds 1-16) + bf16
// convert with dim-XOR swizzle (dim ^ ((code&7)<<3)) + zero loss accumulator.
// ---------------------------------------------------------------------------
__global__ __launch_bounds__(256) void prep_kernel(
    const float* __restrict__ cb, unsigned short* __restrict__ cb16s,
    float* __restrict__ cnorm, float* __restrict__ loss_accum)
{
    const int row = blockIdx.x * 256 + threadIdx.x;   // 0..NQ*NE-1
    if (row == 0) *loss_accum = 0.0f;
    const float* src = cb + (size_t)row * EDIM;
    unsigned short* dst = cb16s + (size_t)row * EDIM;
    const int swz8 = (row & 7) << 3;
    float s = 0.0f;
#pragma unroll
    for (int j = 0; j < EDIM / 4; ++j) {
        float4 v = ((const float4*)src)[j];
        s += v.x * v.x; s += v.y * v.y; s += v.z * v.z; s += v.w * v.w;
        ushort4 o;
        o.x = bf16rne(v.x); o.y = bf16rne(v.y);
        o.z = bf16rne(v.z); o.w = bf16rne(v.w);
        *(ushort4*)(dst + ((j * 4) ^ swz8)) = o;
    }
    cnorm[row] = s;
}

// ---------------------------------------------------------------------------
// FUSED all-4-levels kernel with 3-phase sweep:
//   A: chunks 0..7  T_MIN (warmup min over 512 codes)
//   mid-sync: stale per-token threshold ts = min512 + MARGIN (conservative:
//             min512 >= final min  =>  ts >= final threshold => superset)
//   B: chunks 8..31 fused min+push vs ts
//   final reduce -> exact final thresholds th
//   C: redo chunks 0..7 with T_CAND vs th
// Refine: exact fp32 (rounds 1-16 chain), lex-min; cnt>CAP => full exact
// rescan fallback (same chain; safety only). 40 chunk-units/level vs 64.
// grid = 512 blocks, 256 thr, ~78 KB LDS -> 2 blocks/CU.
// ---------------------------------------------------------------------------
__global__ __launch_bounds__(256, 2) void vq_fused_kernel(
    const float* __restrict__ x,
    const float* __restrict__ cbF0,          // fp32 codebooks [NQ][NE][EDIM]
    const unsigned short* __restrict__ cbL0, // bf16 swizzled codebooks
    const float* __restrict__ cnorm0,        // [NQ][NE]
    float* __restrict__ xq,
    float* __restrict__ idx_out,
    float* __restrict__ loss_accum)
{
    __shared__ __align__(16) float Af[TOKT][132];                  // 33792 B
    __shared__ __align__(16) unsigned short Bs[2][CHCODES * EDIM]; // 32768 B
    __shared__ float part[4 * TOKT];
    __shared__ float rns[TOKT];
    __shared__ float mdw[2][TOKT];
    __shared__ int   cnt[TOKT];
    __shared__ int   lst[TOKT * CAP];                              // 6144 B
    __shared__ float redb_d[4][TOKT];
    __shared__ int   redb_i[4][TOKT];
    __shared__ int   idx_s[TOKT];
    __shared__ float lsum[256];

    const int t     = threadIdx.x;
    const int tok0  = blockIdx.x * TOKT;
    const int w     = t >> 6;
    const int rh    = w >> 1;         // token half
    const int chalf = w & 1;          // code half within each chunk
    const int cl    = t & 15;         // MFMA col lane
    const int lg    = (t & 63) >> 4;  // k-group

    // ---- stage x -> Af (row-major) + partial norms (rounds 1-16 chain) ----
    {
        const int tok = t & 63;
        const int dg  = t >> 6;
        float s = 0.0f;
#pragma unroll
        for (int j = 0; j < 8; ++j) {
            const int d0 = dg * 32 + j * 4;
            float4 v = *(const float4*)(x + (size_t)(tok0 + tok) * EDIM + d0);
            *(float4*)&Af[tok][d0] = v;
            s += v.x * v.x; s += v.y * v.y; s += v.z * v.z; s += v.w * v.w;
        }
        part[dg * TOKT + tok] = s;
    }
    __syncthreads();

    // B read addressing (round-9-verified swizzle; code&7 == cl&7)
    const int swzk = (cl & 7) << 4;
    const int inn0 = (0   + lg * 16) ^ swzk;
    const int inn1 = (64  + lg * 16) ^ swzk;
    const int inn2 = (128 + lg * 16) ^ swzk;
    const int inn3 = (192 + lg * 16) ^ swzk;

    const int tokb0 = rh * 32 + lg * 4;      // C/D row = lg*4 + reg
    const int tokb1 = tokb0 + 16;

#define STAGE(DST, CH) { \
    const char* gs = (const char*)cbL + (size_t)(CH) * 16384 + t * 16; \
    char* ls = (char*)(DST) + (t & 192) * 16; \
    gld16(gs,         ls); \
    gld16(gs + 4096,  ls + 4096); \
    gld16(gs + 8192,  ls + 8192); \
    gld16(gs + 12288, ls + 12288); }

#define MFMAG(BUFC, CH, CT, TAIL) { \
    const char* bp = (const char*)&Bs[BUFC][0] \
                     + (chalf * 32 + (CT) * 16 + cl) * 256; \
    short8v b0 = *(const short8v*)(bp + inn0); \
    short8v b1 = *(const short8v*)(bp + inn1); \
    short8v b2 = *(const short8v*)(bp + inn2); \
    short8v b3 = *(const short8v*)(bp + inn3); \
    f32x4 ac0 = {0.f, 0.f, 0.f, 0.f}; \
    f32x4 ac1 = {0.f, 0.f, 0.f, 0.f}; \
    ac0 = MFMA_BF16(a00, b0, ac0, 0, 0, 0); \
    ac0 = MFMA_BF16(a01, b1, ac0, 0, 0, 0); \
    ac0 = MFMA_BF16(a02, b2, ac0, 0, 0, 0); \
    ac0 = MFMA_BF16(a03, b3, ac0, 0, 0, 0); \
    ac1 = MFMA_BF16(a10, b0, ac1, 0, 0, 0); \
    ac1 = MFMA_BF16(a11, b1, ac1, 0, 0, 0); \
    ac1 = MFMA_BF16(a12, b2, ac1, 0, 0, 0); \
    ac1 = MFMA_BF16(a13, b3, ac1, 0, 0, 0); \
    const int code = (CH) * CHCODES + chalf * 32 + (CT) * 16 + cl; \
    const float cn = cnorm[code]; \
    TAIL }

#define T_MIN \
    md00 = fminf(md00, (rn00 - 2.f * ac0[0]) + cn); \
    md01 = fminf(md01, (rn01 - 2.f * ac0[1]) + cn); \
    md02 = fminf(md02, (rn02 - 2.f * ac0[2]) + cn); \
    md03 = fminf(md03, (rn03 - 2.f * ac0[3]) + cn); \
    md10 = fminf(md10, (rn10 - 2.f * ac1[0]) + cn); \
    md11 = fminf(md11, (rn11 - 2.f * ac1[1]) + cn); \
    md12 = fminf(md12, (rn12 - 2.f * ac1[2]) + cn); \
    md13 = fminf(md13, (rn13 - 2.f * ac1[3]) + cn);

#define PUSH(AC, R, RN, TH, TOKB) { \
    float dd = ((RN) - 2.f * AC[R]) + cn; \
    if (dd < (TH)) { int p = atomicAdd(&cnt[(TOKB) + R], 1); \
                     if (p < CAP) lst[((TOKB) + R) * CAP + p] = code; } }
#define T_CAND \
    PUSH(ac0, 0, rn00, th00, tokb0) PUSH(ac0, 1, rn01, th01, tokb0) \
    PUSH(ac0, 2, rn02, th02, tokb0) PUSH(ac0, 3, rn03, th03, tokb0) \
    PUSH(ac1, 0, rn10, th10, tokb1) PUSH(ac1, 1, rn11, th11, tokb1) \
    PUSH(ac1, 2, rn12, th12, tokb1) PUSH(ac1, 3, rn13, th13, tokb1)

// fused min + push vs STALE threshold ts (conservative superset)
#define MP1(AC, R, RN, TS, MD, TOKB) { \
    const float dd = ((RN) - 2.f * AC[R]) + cn; \
    MD = fminf(MD, dd); \
    if (dd < (TS)) { int p = atomicAdd(&cnt[(TOKB) + R], 1); \
                     if (p < CAP) lst[((TOKB) + R) * CAP + p] = code; } }
#define T_MP \
    MP1(ac0, 0, rn00, ts00, md00, tokb0) MP1(ac0, 1, rn01, ts01, md01, tokb0) \
    MP1(ac0, 2, rn02, ts02, md02, tokb0) MP1(ac0, 3, rn03, ts03, md03, tokb0) \
    MP1(ac1, 0, rn10, ts10, md10, tokb1) MP1(ac1, 1, rn11, ts11, md11, tokb1) \
    MP1(ac1, 2, rn12, ts12, md12, tokb1) MP1(ac1, 3, rn13, ts13, md13, tokb1)

#define CH_MIN(B, CH)  { MFMAG(B, CH, 0, T_MIN)  MFMAG(B, CH, 1, T_MIN)  }
#define CH_MP(B, CH)   { MFMAG(B, CH, 0, T_MP)   MFMAG(B, CH, 1, T_MP)   }
#define CH_CAND(B, CH) { MFMAG(B, CH, 0, T_CAND) MFMAG(B, CH, 1, T_CAND) }

#define REDUCE_MD \
    _Pragma("unroll") \
    for (int m = 1; m < 16; m <<= 1) { \
        md00 = fminf(md00, __shfl_xor(md00, m, 64)); \
        md01 = fminf(md01, __shfl_xor(md01, m, 64)); \
        md02 = fminf(md02, __shfl_xor(md02, m, 64)); \
        md03 = fminf(md03, __shfl_xor(md03, m, 64)); \
        md10 = fminf(md10, __shfl_xor(md10, m, 64)); \
        md11 = fminf(md11, __shfl_xor(md11, m, 64)); \
        md12 = fminf(md12, __shfl_xor(md12, m, 64)); \
        md13 = fminf(md13, __shfl_xor(md13, m, 64)); \
    } \
    if (cl == 0) { \
        mdw[chalf][tokb0 + 0] = md00; mdw[chalf][tokb0 + 1] = md01; \
        mdw[chalf][tokb0 + 2] = md02; mdw[chalf][tokb0 + 3] = md03; \
        mdw[chalf][tokb1 + 0] = md10; mdw[chalf][tokb1 + 1] = md11; \
        mdw[chalf][tokb1 + 2] = md12; mdw[chalf][tokb1 + 3] = md13; \
    }

#pragma unroll 1
    for (int l = 0; l < NQ; ++l) {
        const float* cbF          = cbF0 + (size_t)l * NE * EDIM;
        const unsigned short* cbL = cbL0 + (size_t)l * NE * EDIM;
        const float* cnorm        = cnorm0 + (size_t)l * NE;

        if (t < TOKT) {
            rns[t] = ((part[t] + part[TOKT + t]) + part[2 * TOKT + t])
                     + part[3 * TOKT + t];
            cnt[t] = 0;
        }

        // ---- A fragments: 2 row-tiles x 4 kt from Af (LDS) ----
        short8v a00, a01, a02, a03, a10, a11, a12, a13;
#define LDA(AF, AROW, KT) { \
    float4 p0 = *(const float4*)&Af[AROW][(KT) * 32 + lg * 8]; \
    float4 p1 = *(const float4*)&Af[AROW][(KT) * 32 + lg * 8 + 4]; \
    AF[0] = (short)bf16rne(p0.x); AF[1] = (short)bf16rne(p0.y); \
    AF[2] = (short)bf16rne(p0.z); AF[3] = (short)bf16rne(p0.w); \
    AF[4] = (short)bf16rne(p1.x); AF[5] = (short)bf16rne(p1.y); \
    AF[6] = (short)bf16rne(p1.z); AF[7] = (short)bf16rne(p1.w); }
        {
            const int ar0 = rh * 32 + cl, ar1 = rh * 32 + 16 + cl;
            LDA(a00, ar0, 0) LDA(a01, ar0, 1) LDA(a02, ar0, 2) LDA(a03, ar0, 3)
            LDA(a10, ar1, 0) LDA(a11, ar1, 1) LDA(a12, ar1, 2) LDA(a13, ar1, 3)
        }
#undef LDA

        STAGE(&Bs[0][0], 0)
        __syncthreads();                 // chunk0 resident; rns/cnt visible

        const float rn00 = rns[tokb0 + 0], rn01 = rns[tokb0 + 1];
        const float rn02 = rns[tokb0 + 2], rn03 = rns[tokb0 + 3];
        const float rn10 = rns[tokb1 + 0], rn11 = rns[tokb1 + 1];
        const float rn12 = rns[tokb1 + 2], rn13 = rns[tokb1 + 3];

        float md00 = 3.402823466e38f, md01 = md00, md02 = md00, md03 = md00;
        float md10 = md00, md11 = md00, md12 = md00, md13 = md00;

        // ---- PHASE A: chunks 0..7, min only ----
        for (int c2 = 0; c2 < NWARM / 2; ++c2) {
            const int c = c2 * 2;
            STAGE(&Bs[1][0], c + 1)
            CH_MIN(0, c)
            __syncthreads();
            STAGE(&Bs[0][0], c + 2)      // c+2 <= 8 == phase-B first chunk
            CH_MIN(1, c + 1)
            __syncthreads();
        }

        // ---- mid-sync: stale thresholds ts = min512 + MARGIN ----
        REDUCE_MD
        __syncthreads();                 // mdw visible (chunk-8 staging drains)
        const float ts00 = fminf(mdw[0][tokb0 + 0], mdw[1][tokb0 + 0]) + MARGIN;
        const float ts01 = fminf(mdw[0][tokb0 + 1], mdw[1][tokb0 + 1]) + MARGIN;
        const float ts02 = fminf(mdw[0][tokb0 + 2], mdw[1][tokb0 + 2]) + MARGIN;
        const float ts03 = fminf(mdw[0][tokb0 + 3], mdw[1][tokb0 + 3]) + MARGIN;
        const float ts10 = fminf(mdw[0][tokb1 + 0], mdw[1][tokb1 + 0]) + MARGIN;
        const float ts11 = fminf(mdw[0][tokb1 + 1], mdw[1][tokb1 + 1]) + MARGIN;
        const float ts12 = fminf(mdw[0][tokb1 + 2], mdw[1][tokb1 + 2]) + MARGIN;
        const float ts13 = fminf(mdw[0][tokb1 + 3], mdw[1][tokb1 + 3]) + MARGIN;

        // ---- PHASE B: chunks 8..31, fused min+push vs ts ----
        for (int c2 = 0; c2 < (NCHUNK - NWARM) / 2; ++c2) {
            const int c = NWARM + c2 * 2;
            STAGE(&Bs[1][0], c + 1)
            CH_MP(0, c)
            __syncthreads();
            if (c + 2 < NCHUNK) { STAGE(&Bs[0][0], c + 2) }
            else                { STAGE(&Bs[0][0], 0) }   // phase-C chunk 0
            CH_MP(1, c + 1)
            __syncthreads();
        }

        // ---- final reduce: exact final thresholds ----
        REDUCE_MD
        __syncthreads();                 // mdw visible (chunk-0 staging drains)
        const float th00 = fminf(mdw[0][tokb0 + 0], mdw[1][tokb0 + 0]) + MARGIN;
        const float th01 = fminf(mdw[0][tokb0 + 1], mdw[1][tokb0 + 1]) + MARGIN;
        const float th02 = fminf(mdw[0][tokb0 + 2], mdw[1][tokb0 + 2]) + MARGIN;
        const float th03 = fminf(mdw[0][tokb0 + 3], mdw[1][tokb0 + 3]) + MARGIN;
        const float th10 = fminf(mdw[0][tokb1 + 0], mdw[1][tokb1 + 0]) + MARGIN;
        const float th11 = fminf(mdw[0][tokb1 + 1], mdw[1][tokb1 + 1]) + MARGIN;
        const float th12 = fminf(mdw[0][tokb1 + 2], mdw[1][tokb1 + 2]) + MARGIN;
        const float th13 = fminf(mdw[0][tokb1 + 3], mdw[1][tokb1 + 3]) + MARGIN;

        // ---- PHASE C: redo chunks 0..7 with final thresholds ----
        for (int c2 = 0; c2 < NWARM / 2; ++c2) {
            const int c = c2 * 2;
            STAGE(&Bs[1][0], c + 1)
            CH_CAND(0, c)
            __syncthreads();
            if (c + 2 < NWARM) STAGE(&Bs[0][0], c + 2)
            CH_CAND(1, c + 1)
            __syncthreads();
        }

        // ---- refine: exact fp32 (rounds 1-16 chain), 4-way per token ----
        {
            const int tok = t & 63;
            const int s   = t >> 6;
            const int n   = cnt[tok];
            const float rn_t = rns[tok];
            float bd = 3.402823466e38f;
            int   bi = 0x7fffffff;
            if (n > CAP) {
                // overflow fallback: full exact scan (same chain; safety net)
                for (int c = s; c < NE; c += 4) {
                    const float* cr = cbF + (size_t)c * EDIM;
                    float dot = 0.0f;
#pragma unroll 8
                    for (int d = 0; d < EDIM; ++d)
                        dot = fmaf(Af[tok][d], cr[d], dot);
                    const float dd = (rn_t - 2.0f * dot) + cnorm[c];
                    if (dd < bd || (dd == bd && c < bi)) { bd = dd; bi = c; }
                }
            } else {
                for (int i = s; i < n; i += 4) {
                    const int c = lst[tok * CAP + i];
                    const float* cr = cbF + (size_t)c * EDIM;
                    float dot = 0.0f;
#pragma unroll 8
                    for (int d = 0; d < EDIM; ++d)
                        dot = fmaf(Af[tok][d], cr[d], dot);
                    const float dd = (rn_t - 2.0f * dot) + cnorm[c];
                    if (dd < bd || (dd == bd && c < bi)) { bd = dd; bi = c; }
                }
            }
            redb_d[s][tok] = bd;
            redb_i[s][tok] = bi;
        }
        __syncthreads();
        if (t < TOKT) {
            float bd = redb_d[0][t];
            int   bi = redb_i[0][t];
#pragma unroll
            for (int s = 1; s < 4; ++s) {
                const float dd = redb_d[s][t];
                const int   ii = redb_i[s][t];
                if (dd < bd || (dd == bd && ii < bi)) { bd = dd; bi = ii; }
            }
            idx_s[t] = bi;
            idx_out[(size_t)(tok0 + t) * NQ + l] = (float)bi;
        }
        __syncthreads();

        // ---- epilogue: gather + straight-through; Af <- r_next in place ----
        {
            const int tok = t >> 2;
            const int dq  = t & 3;
            const int gi  = idx_s[tok];
            const float* qrow = cbF + (size_t)gi * EDIM;
            float lp = 0.0f;
#pragma unroll
            for (int k = 0; k < 8; ++k) {
                const int d0 = k * 16 + dq * 4;
                const float4 q = *(const float4*)(qrow + d0);
                const float4 r = *(const float4*)&Af[tok][d0];
                float4 tq, qst, rnv;
                tq.x = q.x - r.x; tq.y = q.y - r.y;
                tq.z = q.z - r.z; tq.w = q.w - r.w;
                qst.x = r.x + tq.x; qst.y = r.y + tq.y;
                qst.z = r.z + tq.z; qst.w = r.w + tq.w;
                rnv.x = r.x - qst.x; rnv.y = r.y - qst.y;
                rnv.z = r.z - qst.z; rnv.w = r.w - qst.w;
                *(float4*)&Af[tok][d0] = rnv;                  // residual update
                const size_t go = (size_t)(tok0 + tok) * EDIM + d0;
                if (l == 0) {
                    *(float4*)(xq + go) = qst;
                } else {
                    float4 o = *(const float4*)(xq + go);
                    o.x += qst.x; o.y += qst.y; o.z += qst.z; o.w += qst.w;
                    *(float4*)(xq + go) = o;
                }
                lp += tq.x * tq.x; lp += tq.y * tq.y;
                lp += tq.z * tq.z; lp += tq.w * tq.w;
            }
            lsum[t] = lp;
        }
        __syncthreads();
#pragma unroll
        for (int s2 = 128; s2 > 0; s2 >>= 1) {
            if (t < s2) lsum[t] += lsum[t + s2];
            __syncthreads();
        }
        if (t == 0) atomicAdd(loss_accum, lsum[0]);

        // ---- recompute norm partials from updated Af (same association) ----
        if (l + 1 < NQ) {
            const int tok = t & 63;
            const int dg  = t >> 6;
            float s = 0.0f;
#pragma unroll
            for (int j = 0; j < 8; ++j) {
                const int d0 = dg * 32 + j * 4;
                const float4 v = *(const float4*)&Af[tok][d0];
                s += v.x * v.x; s += v.y * v.y;
                s += v.z * v.z; s += v.w * v.w;
            }
            part[dg * TOKT + tok] = s;
        }
        __syncthreads();
    }
}

// ---------------------------------------------------------------------------
__global__ void finalize_kernel(const float* __restrict__ loss_accum,
                                float* __restrict__ out_loss)
{
    *out_loss = *loss_accum * (1.25f / (4.0f * (float)NTOK * (float)EDIM));
}

extern "C" void kernel_launch(void* const* d_in, const int* in_sizes, int n_in,
                              void* d_out, int out_size, void* d_ws, size_t ws_size,
                              hipStream_t stream)
{
    const float* x  = (const float*)d_in[0];
    const float* cb = (const float*)d_in[1];

    float* out      = (float*)d_out;
    float* xq       = out;
    float* out_loss = out + (size_t)NTOK * EDIM;
    float* idx_out  = out + (size_t)NTOK * EDIM + 1;

    float* ws             = (float*)d_ws;
    float* cnorm          = ws;                            // NQ*NE
    float* loss_accum     = ws + 8192;
    unsigned short* cb16s = (unsigned short*)(ws + 8448);  // NQ*NE*EDIM bf16

    prep_kernel<<<(NQ * NE) / 256, 256, 0, stream>>>(cb, cb16s, cnorm, loss_accum);

    vq_fused_kernel<<<NTOK / TOKT, 256, 0, stream>>>(
        x, cb, cb16s, cnorm, xq, idx_out, loss_accum);

    finalize_kernel<<<1, 1, 0, stream>>>(loss_accum, out_loss);
}

// Round 18
// 251.075 us; speedup vs baseline: 17.4764x; 17.4764x over previous
//
#include <hip/hip_runtime.h>

#define NTOK 32768
#define NE   2048
#define EDIM 128
#define NQ   4

#define TOKT 64                  // tokens per block
#define CHCODES 64               // codes per staged chunk (16 KB bf16)
#define NCHUNK (NE / CHCODES)    // 32
#define CAP 16
#define MARGIN 0.25f             // d-space margin (r11/r16-proven)

typedef __attribute__((ext_vector_type(8))) short short8v;   // 8 bf16
typedef __attribute__((ext_vector_type(4))) float f32x4;

__device__ __forceinline__ unsigned short bf16rne(float x) {
    unsigned u = __float_as_uint(x);
    unsigned r = 0x7FFFu + ((u >> 16) & 1u);
    return (unsigned short)((u + r) >> 16);
}

__device__ __forceinline__ void gld16(const void* g, const void* l) {
    __builtin_amdgcn_global_load_lds(
        (const __attribute__((address_space(1))) unsigned int*)g,
        (__attribute__((address_space(3))) unsigned int*)l, 16, 0, 0);
}

#define MFMA_BF16 __builtin_amdgcn_mfma_f32_16x16x32_bf16

// ---------------------------------------------------------------------------
// prep: per-code fp32 norms (identical serial chain to rounds 1-17) + bf16
// convert with dim-XOR swizzle (dim ^ ((code&7)<<3)) + zero loss accumulator.
// ---------------------------------------------------------------------------
__global__ __launch_bounds__(256) void prep_kernel(
    const float* __restrict__ cb, unsigned short* __restrict__ cb16s,
    float* __restrict__ cnorm, float* __restrict__ loss_accum)
{
    const int row = blockIdx.x * 256 + threadIdx.x;   // 0..NQ*NE-1
    if (row == 0) *loss_accum = 0.0f;
    const float* src = cb + (size_t)row * EDIM;
    unsigned short* dst = cb16s + (size_t)row * EDIM;
    const int swz8 = (row & 7) << 3;
    float s = 0.0f;
#pragma unroll
    for (int j = 0; j < EDIM / 4; ++j) {
        float4 v = ((const float4*)src)[j];
        s += v.x * v.x; s += v.y * v.y; s += v.z * v.z; s += v.w * v.w;
        ushort4 o;
        o.x = bf16rne(v.x); o.y = bf16rne(v.y);
        o.z = bf16rne(v.z); o.w = bf16rne(v.w);
        *(ushort4*)(dst + ((j * 4) ^ swz8)) = o;
    }
    cnorm[row] = s;
}

// ---------------------------------------------------------------------------
// FUSED all-4-levels kernel (r16 structure, reverted from r17's failed
// 3-phase sieve). Block owns 64 tokens; residual lives in Af (LDS) across
// levels. Per level: 2-pass bf16-MFMA sieve + exact-fp32 refine. NEW vs r16:
// xq is TELESCOPED — q_st_l = r_l - r_(l+1)  =>  xq = x - r_final, written
// once after the level loop (removes 64 MB W + 48 MB R of per-level RMW).
// grid = 512 blocks, 256 thr, ~76 KB LDS -> 2 blocks/CU.
// ---------------------------------------------------------------------------
__global__ __launch_bounds__(256, 2) void vq_fused_kernel(
    const float* __restrict__ x,
    const float* __restrict__ cbF0,          // fp32 codebooks [NQ][NE][EDIM]
    const unsigned short* __restrict__ cbL0, // bf16 swizzled codebooks
    const float* __restrict__ cnorm0,        // [NQ][NE]
    float* __restrict__ xq,
    float* __restrict__ idx_out,
    float* __restrict__ loss_accum)
{
    __shared__ __align__(16) float Af[TOKT][132];                  // 33792 B
    __shared__ __align__(16) unsigned short Bs[2][CHCODES * EDIM]; // 32768 B
    __shared__ float part[4 * TOKT];
    __shared__ float rns[TOKT];
    __shared__ float mdw[2][TOKT];
    __shared__ int   cnt[TOKT];
    __shared__ int   lst[TOKT * CAP];
    __shared__ float redb_d[4][TOKT];
    __shared__ int   redb_i[4][TOKT];
    __shared__ int   idx_s[TOKT];
    __shared__ float lsum[256];

    const int t     = threadIdx.x;
    const int tok0  = blockIdx.x * TOKT;
    const int w     = t >> 6;
    const int rh    = w >> 1;         // token half
    const int chalf = w & 1;          // code half within each chunk
    const int cl    = t & 15;         // MFMA col lane
    const int lg    = (t & 63) >> 4;  // k-group

    // ---- stage x -> Af (row-major) + partial norms (rounds 1-17 chain) ----
    {
        const int tok = t & 63;
        const int dg  = t >> 6;
        float s = 0.0f;
#pragma unroll
        for (int j = 0; j < 8; ++j) {
            const int d0 = dg * 32 + j * 4;
            float4 v = *(const float4*)(x + (size_t)(tok0 + tok) * EDIM + d0);
            *(float4*)&Af[tok][d0] = v;
            s += v.x * v.x; s += v.y * v.y; s += v.z * v.z; s += v.w * v.w;
        }
        part[dg * TOKT + tok] = s;
    }
    __syncthreads();

    // B read addressing (round-9-verified swizzle; code&7 == cl&7)
    const int swzk = (cl & 7) << 4;
    const int inn0 = (0   + lg * 16) ^ swzk;
    const int inn1 = (64  + lg * 16) ^ swzk;
    const int inn2 = (128 + lg * 16) ^ swzk;
    const int inn3 = (192 + lg * 16) ^ swzk;

    const int tokb0 = rh * 32 + lg * 4;      // C/D row = lg*4 + reg
    const int tokb1 = tokb0 + 16;

#define STAGE(DST, CH) { \
    const char* gs = (const char*)cbL + (size_t)(CH) * 16384 + t * 16; \
    char* ls = (char*)(DST) + (t & 192) * 16; \
    gld16(gs,         ls); \
    gld16(gs + 4096,  ls + 4096); \
    gld16(gs + 8192,  ls + 8192); \
    gld16(gs + 12288, ls + 12288); }

#define MFMAG(BUFC, CH, CT, TAIL) { \
    const char* bp = (const char*)&Bs[BUFC][0] \
                     + (chalf * 32 + (CT) * 16 + cl) * 256; \
    short8v b0 = *(const short8v*)(bp + inn0); \
    short8v b1 = *(const short8v*)(bp + inn1); \
    short8v b2 = *(const short8v*)(bp + inn2); \
    short8v b3 = *(const short8v*)(bp + inn3); \
    f32x4 ac0 = {0.f, 0.f, 0.f, 0.f}; \
    f32x4 ac1 = {0.f, 0.f, 0.f, 0.f}; \
    ac0 = MFMA_BF16(a00, b0, ac0, 0, 0, 0); \
    ac0 = MFMA_BF16(a01, b1, ac0, 0, 0, 0); \
    ac0 = MFMA_BF16(a02, b2, ac0, 0, 0, 0); \
    ac0 = MFMA_BF16(a03, b3, ac0, 0, 0, 0); \
    ac1 = MFMA_BF16(a10, b0, ac1, 0, 0, 0); \
    ac1 = MFMA_BF16(a11, b1, ac1, 0, 0, 0); \
    ac1 = MFMA_BF16(a12, b2, ac1, 0, 0, 0); \
    ac1 = MFMA_BF16(a13, b3, ac1, 0, 0, 0); \
    const int code = (CH) * CHCODES + chalf * 32 + (CT) * 16 + cl; \
    const float cn = cnorm[code]; \
    TAIL }

#define T_MIN \
    md00 = fminf(md00, (rn00 - 2.f * ac0[0]) + cn); \
    md01 = fminf(md01, (rn01 - 2.f * ac0[1]) + cn); \
    md02 = fminf(md02, (rn02 - 2.f * ac0[2]) + cn); \
    md03 = fminf(md03, (rn03 - 2.f * ac0[3]) + cn); \
    md10 = fminf(md10, (rn10 - 2.f * ac1[0]) + cn); \
    md11 = fminf(md11, (rn11 - 2.f * ac1[1]) + cn); \
    md12 = fminf(md12, (rn12 - 2.f * ac1[2]) + cn); \
    md13 = fminf(md13, (rn13 - 2.f * ac1[3]) + cn);

#define PUSH(AC, R, RN, TH, TOKB) { \
    float dd = ((RN) - 2.f * AC[R]) + cn; \
    if (dd < (TH)) { int p = atomicAdd(&cnt[(TOKB) + R], 1); \
                     if (p < CAP) lst[((TOKB) + R) * CAP + p] = code; } }
#define T_CAND \
    PUSH(ac0, 0, rn00, th00, tokb0) PUSH(ac0, 1, rn01, th01, tokb0) \
    PUSH(ac0, 2, rn02, th02, tokb0) PUSH(ac0, 3, rn03, th03, tokb0) \
    PUSH(ac1, 0, rn10, th10, tokb1) PUSH(ac1, 1, rn11, th11, tokb1) \
    PUSH(ac1, 2, rn12, th12, tokb1) PUSH(ac1, 3, rn13, th13, tokb1)

#define CH_P1(B, CH) { MFMAG(B, CH, 0, T_MIN)  MFMAG(B, CH, 1, T_MIN)  }
#define CH_P2(B, CH) { MFMAG(B, CH, 0, T_CAND) MFMAG(B, CH, 1, T_CAND) }

#pragma unroll 1
    for (int l = 0; l < NQ; ++l) {
        const float* cbF          = cbF0 + (size_t)l * NE * EDIM;
        const unsigned short* cbL = cbL0 + (size_t)l * NE * EDIM;
        const float* cnorm        = cnorm0 + (size_t)l * NE;

        if (t < TOKT) {
            rns[t] = ((part[t] + part[TOKT + t]) + part[2 * TOKT + t])
                     + part[3 * TOKT + t];
            cnt[t] = 0;
        }

        // ---- A fragments: 2 row-tiles x 4 kt from Af (LDS) ----
        short8v a00, a01, a02, a03, a10, a11, a12, a13;
#define LDA(AF, AROW, KT) { \
    float4 p0 = *(const float4*)&Af[AROW][(KT) * 32 + lg * 8]; \
    float4 p1 = *(const float4*)&Af[AROW][(KT) * 32 + lg * 8 + 4]; \
    AF[0] = (short)bf16rne(p0.x); AF[1] = (short)bf16rne(p0.y); \
    AF[2] = (short)bf16rne(p0.z); AF[3] = (short)bf16rne(p0.w); \
    AF[4] = (short)bf16rne(p1.x); AF[5] = (short)bf16rne(p1.y); \
    AF[6] = (short)bf16rne(p1.z); AF[7] = (short)bf16rne(p1.w); }
        {
            const int ar0 = rh * 32 + cl, ar1 = rh * 32 + 16 + cl;
            LDA(a00, ar0, 0) LDA(a01, ar0, 1) LDA(a02, ar0, 2) LDA(a03, ar0, 3)
            LDA(a10, ar1, 0) LDA(a11, ar1, 1) LDA(a12, ar1, 2) LDA(a13, ar1, 3)
        }
#undef LDA

        // ---- PASS 1: per-token min of approx distance ----
        STAGE(&Bs[0][0], 0)
        __syncthreads();                 // chunk0 resident; rns visible

        const float rn00 = rns[tokb0 + 0], rn01 = rns[tokb0 + 1];
        const float rn02 = rns[tokb0 + 2], rn03 = rns[tokb0 + 3];
        const float rn10 = rns[tokb1 + 0], rn11 = rns[tokb1 + 1];
        const float rn12 = rns[tokb1 + 2], rn13 = rns[tokb1 + 3];

        float md00 = 3.402823466e38f, md01 = md00, md02 = md00, md03 = md00;
        float md10 = md00, md11 = md00, md12 = md00, md13 = md00;

        for (int c2 = 0; c2 < NCHUNK / 2; ++c2) {
            const int c = c2 * 2;
            STAGE(&Bs[1][0], c + 1)
            CH_P1(0, c)
            __syncthreads();
            if (c + 2 < NCHUNK) STAGE(&Bs[0][0], c + 2)
            CH_P1(1, c + 1)
            __syncthreads();
        }

        // reduce min across the 16 code-lanes (cl), then across wave pair
#pragma unroll
        for (int m = 1; m < 16; m <<= 1) {
            md00 = fminf(md00, __shfl_xor(md00, m, 64));
            md01 = fminf(md01, __shfl_xor(md01, m, 64));
            md02 = fminf(md02, __shfl_xor(md02, m, 64));
            md03 = fminf(md03, __shfl_xor(md03, m, 64));
            md10 = fminf(md10, __shfl_xor(md10, m, 64));
            md11 = fminf(md11, __shfl_xor(md11, m, 64));
            md12 = fminf(md12, __shfl_xor(md12, m, 64));
            md13 = fminf(md13, __shfl_xor(md13, m, 64));
        }
        if (cl == 0) {
            mdw[chalf][tokb0 + 0] = md00; mdw[chalf][tokb0 + 1] = md01;
            mdw[chalf][tokb0 + 2] = md02; mdw[chalf][tokb0 + 3] = md03;
            mdw[chalf][tokb1 + 0] = md10; mdw[chalf][tokb1 + 1] = md11;
            mdw[chalf][tokb1 + 2] = md12; mdw[chalf][tokb1 + 3] = md13;
        }

        // ---- PASS 2 prologue: stage chunk0 while combining mins ----
        STAGE(&Bs[0][0], 0)
        __syncthreads();                 // mdw visible + chunk0 resident

        const float th00 = fminf(mdw[0][tokb0 + 0], mdw[1][tokb0 + 0]) + MARGIN;
        const float th01 = fminf(mdw[0][tokb0 + 1], mdw[1][tokb0 + 1]) + MARGIN;
        const float th02 = fminf(mdw[0][tokb0 + 2], mdw[1][tokb0 + 2]) + MARGIN;
        const float th03 = fminf(mdw[0][tokb0 + 3], mdw[1][tokb0 + 3]) + MARGIN;
        const float th10 = fminf(mdw[0][tokb1 + 0], mdw[1][tokb1 + 0]) + MARGIN;
        const float th11 = fminf(mdw[0][tokb1 + 1], mdw[1][tokb1 + 1]) + MARGIN;
        const float th12 = fminf(mdw[0][tokb1 + 2], mdw[1][tokb1 + 2]) + MARGIN;
        const float th13 = fminf(mdw[0][tokb1 + 3], mdw[1][tokb1 + 3]) + MARGIN;

        for (int c2 = 0; c2 < NCHUNK / 2; ++c2) {
            const int c = c2 * 2;
            STAGE(&Bs[1][0], c + 1)
            CH_P2(0, c)
            __syncthreads();
            if (c + 2 < NCHUNK) STAGE(&Bs[0][0], c + 2)
            CH_P2(1, c + 1)
            __syncthreads();
        }

        // ---- refine: exact fp32 (rounds 1-17 chain), 4-way per token ----
        {
            const int tok = t & 63;
            const int s   = t >> 6;
            const int n   = min(cnt[tok], CAP);
            const float rn_t = rns[tok];
            float bd = 3.402823466e38f;
            int   bi = 0x7fffffff;
            for (int i = s; i < n; i += 4) {
                const int c = lst[tok * CAP + i];
                const float* cr = cbF + (size_t)c * EDIM;
                float dot = 0.0f;
#pragma unroll 8
                for (int d = 0; d < EDIM; ++d)
                    dot = fmaf(Af[tok][d], cr[d], dot);
                const float dd = (rn_t - 2.0f * dot) + cnorm[c];
                if (dd < bd || (dd == bd && c < bi)) { bd = dd; bi = c; }
            }
            redb_d[s][tok] = bd;
            redb_i[s][tok] = bi;
        }
        __syncthreads();
        if (t < TOKT) {
            float bd = redb_d[0][t];
            int   bi = redb_i[0][t];
#pragma unroll
            for (int s = 1; s < 4; ++s) {
                const float dd = redb_d[s][t];
                const int   ii = redb_i[s][t];
                if (dd < bd || (dd == bd && ii < bi)) { bd = dd; bi = ii; }
            }
            idx_s[t] = bi;
            idx_out[(size_t)(tok0 + t) * NQ + l] = (float)bi;
        }
        __syncthreads();

        // ---- epilogue: gather + straight-through; Af <- r_next in place.
        //      NO xq RMW (telescoped: xq = x - r_final, written after loop) ----
        {
            const int tok = t >> 2;
            const int dq  = t & 3;
            const int gi  = idx_s[tok];
            const float* qrow = cbF + (size_t)gi * EDIM;
            float lp = 0.0f;
#pragma unroll
            for (int k = 0; k < 8; ++k) {
                const int d0 = k * 16 + dq * 4;
                const float4 q = *(const float4*)(qrow + d0);
                const float4 r = *(const float4*)&Af[tok][d0];
                float4 tq, qst, rnv;
                tq.x = q.x - r.x; tq.y = q.y - r.y;
                tq.z = q.z - r.z; tq.w = q.w - r.w;
                qst.x = r.x + tq.x; qst.y = r.y + tq.y;
                qst.z = r.z + tq.z; qst.w = r.w + tq.w;
                rnv.x = r.x - qst.x; rnv.y = r.y - qst.y;
                rnv.z = r.z - qst.z; rnv.w = r.w - qst.w;
                *(float4*)&Af[tok][d0] = rnv;                  // residual update
                lp += tq.x * tq.x; lp += tq.y * tq.y;
                lp += tq.z * tq.z; lp += tq.w * tq.w;
            }
            lsum[t] = lp;
        }
        __syncthreads();
#pragma unroll
        for (int s2 = 128; s2 > 0; s2 >>= 1) {
            if (t < s2) lsum[t] += lsum[t + s2];
            __syncthreads();
        }
        if (t == 0) atomicAdd(loss_accum, lsum[0]);

        // ---- recompute norm partials from updated Af (same association) ----
        if (l + 1 < NQ) {
            const int tok = t & 63;
            const int dg  = t >> 6;
            float s = 0.0f;
#pragma unroll
            for (int j = 0; j < 8; ++j) {
                const int d0 = dg * 32 + j * 4;
                const float4 v = *(const float4*)&Af[tok][d0];
                s += v.x * v.x; s += v.y * v.y;
                s += v.z * v.z; s += v.w * v.w;
            }
            part[dg * TOKT + tok] = s;
        }
        __syncthreads();
    }

    // ---- final: xq = x - r_final (telescoped straight-through sum) ----
    {
        const int tok = t >> 2;
        const int dq  = t & 3;
#pragma unroll
        for (int k = 0; k < 8; ++k) {
            const int d0 = k * 16 + dq * 4;
            const size_t go = (size_t)(tok0 + tok) * EDIM + d0;
            const float4 xv = *(const float4*)(x + go);
            const float4 rv = *(const float4*)&Af[tok][d0];
            float4 o;
            o.x = xv.x - rv.x; o.y = xv.y - rv.y;
            o.z = xv.z - rv.z; o.w = xv.w - rv.w;
            *(float4*)(xq + go) = o;
        }
    }
}

// ---------------------------------------------------------------------------
__global__ void finalize_kernel(const float* __restrict__ loss_accum,
                                float* __restrict__ out_loss)
{
    *out_loss = *loss_accum * (1.25f / (4.0f * (float)NTOK * (float)EDIM));
}

extern "C" void kernel_launch(void* const* d_in, const int* in_sizes, int n_in,
                              void* d_out, int out_size, void* d_ws, size_t ws_size,
                              hipStream_t stream)
{
    const float* x  = (const float*)d_in[0];
    const float* cb = (const float*)d_in[1];

    float* out      = (float*)d_out;
    float* xq       = out;
    float* out_loss = out + (size_t)NTOK * EDIM;
    float* idx_out  = out + (size_t)NTOK * EDIM + 1;

    float* ws             = (float*)d_ws;
    float* cnorm          = ws;                            // NQ*NE
    float* loss_accum     = ws + 8192;
    unsigned short* cb16s = (unsigned short*)(ws + 8448);  // NQ*NE*EDIM bf16

    prep_kernel<<<(NQ * NE) / 256, 256, 0, stream>>>(cb, cb16s, cnorm, loss_accum);

    vq_fused_kernel<<<NTOK / TOKT, 256, 0, stream>>>(
        x, cb, cb16s, cnorm, xq, idx_out, loss_accum);

    finalize_kernel<<<1, 1, 0, stream>>>(loss_accum, out_loss);
}